// Round 1
// 201.852 us; speedup vs baseline: 1.0070x; 1.0070x over previous
//
#include <hip/hip_runtime.h>

#define S 7
#define NB 2
#define NC 80
#define NBOX 20
#define CELLS 49
#define CH 85                   // 5 + NC
#define PAIR 170                // NB*CH floats per cell
#define PER_B 8330              // CELLS*PAIR floats per image
#define NIMG 4096
#define IMGS_PER_BLK 2
#define NPAIR (NIMG/IMGS_PER_BLK)          // 2048 blocks
#define F4_PER_PAIR (PER_B*IMGS_PER_BLK/4) // 4165 float4 per pair (exact)
#define CELLS2 (CELLS*IMGS_PER_BLK)        // 98
#define L_COORD 5.0f
#define L_NOOBJ 0.5f

// ---------------- block reduce helper (256 threads) ----------------
__device__ __forceinline__ void block_reduce_store(float acc, float* dst)
{
    __shared__ float s_wsum[4];
    int tid = threadIdx.x;
    #pragma unroll
    for (int off = 32; off > 0; off >>= 1) acc += __shfl_down(acc, off, 64);
    int lane = tid & 63, wv = tid >> 6;
    if (lane == 0) s_wsum[wv] = acc;
    __syncthreads();
    if (tid == 0) *dst = s_wsum[0] + s_wsum[1] + s_wsum[2] + s_wsum[3];
}

// ---------------- weighted-square element helpers (weights from LDS) -------
__device__ __forceinline__ float elem1(float p, int r, float4 w)
{
    int nb = (r >= CH) ? 1 : 0;
    int rr = r - nb * CH;
    float wconf = nb ? w.z : w.x;
    float wcls  = nb ? w.w : w.y;
    float m = (rr >= 5) ? wcls : ((rr == 4) ? wconf : 0.0f);
    return m * p * p;
}

__device__ __forceinline__ float elem4(float4 v, int e, const float4* s_wq)
{
    // e is the pair-local float4 index (0..4164); ff in [0, 16660)
    unsigned ff = 4u * (unsigned)e;
    unsigned c0 = ff / (unsigned)PAIR;          // magic-mul, c0 in [0,98)
    int r0 = (int)(ff - c0 * (unsigned)PAIR);   // even; straddle only at 168
    float4 w0 = s_wq[c0];
    float4 w1 = w0;
    bool wrap = (r0 == PAIR - 2);               // only for even c0 -> c0+1 <= 97
    if (wrap) w1 = s_wq[c0 + 1];
    int r2 = wrap ? 0 : r0 + 2;
    float a;
    a  = elem1(v.x, r0,     w0);
    a += elem1(v.y, r0 + 1, w0);
    a += elem1(v.z, r2,     w1);
    a += elem1(v.w, r2 + 1, w1);
    return a;
}

// ---------------- fused kernel: prep (in LDS) + stream ----------------
__global__ __launch_bounds__(256) void fused_kernel(
    const float4* __restrict__ p4,      // predictions as float4
    const float4* __restrict__ boxes4,  // [NIMG*NBOX] one float4 per box
    const int*    __restrict__ labels,
    float*        __restrict__ partial) // [NPAIR]
{
    __shared__ int    s_winner[CELLS2];
    __shared__ float  s_cx[IMGS_PER_BLK * NBOX], s_cy[IMGS_PER_BLK * NBOX];
    __shared__ float  s_bw[IMGS_PER_BLK * NBOX], s_bh[IMGS_PER_BLK * NBOX];
    __shared__ int    s_lab[IMGS_PER_BLK * NBOX];
    __shared__ float4 s_wq[CELLS2];

    const int pb  = blockIdx.x;
    const int tid = threadIdx.x;

    if (tid < CELLS2) s_winner[tid] = NBOX;
    __syncthreads();

    // Phase A: 40 boxes (2 images) -> cells, winner = min box index per cell
    if (tid < IMGS_PER_BLK * NBOX) {
        int img = tid / NBOX, bxi = tid - img * NBOX;
        size_t gbox = (size_t)(pb * IMGS_PER_BLK + img) * NBOX + bxi;
        float4 bx = boxes4[gbox];
        float x = (bx.x + bx.z) * 0.5f, y = (bx.y + bx.w) * 0.5f;
        s_cx[tid] = x; s_cy[tid] = y;
        s_bw[tid] = bx.z - bx.x; s_bh[tid] = bx.w - bx.y;
        s_lab[tid] = labels[gbox];
        int j = (int)floorf(x * (float)S); j = min(max(j, 0), S - 1);
        int i = (int)floorf(y * (float)S); i = min(max(i, 0), S - 1);
        atomicMin(&s_winner[img * CELLS + i * S + j], bxi);
    }
    __syncthreads();

    // Phase B: responsible box per cell -> weight quad in LDS + corrections
    float acc = 0.0f;
    if (tid < CELLS2) {
        int img  = tid / CELLS;
        int cell = tid - img * CELLS;
        int w    = s_winner[tid];
        float4 wq;
        if (w < NBOX) {
            int i = cell / S, j = cell - (cell / S) * S;
            int bi = img * NBOX + w;
            float x = s_cx[bi], y = s_cy[bi];
            float tx = x * (float)S - (float)j;
            float ty = y * (float)S - (float)i;
            float tw = s_bw[bi], th = s_bh[bi];

            const float* p = (const float*)p4
                           + (size_t)(pb * IMGS_PER_BLK + img) * PER_B
                           + (size_t)cell * PAIR;
            float bx1 = tx - tw * 0.5f, by1 = ty - th * 0.5f;
            float bx2 = tx + tw * 0.5f, by2 = ty + th * 0.5f;
            float barea = (bx2 - bx1) * (by2 - by1);
            float iou[2], px[2], py[2], pw[2], ph[2];
            #pragma unroll
            for (int nb = 0; nb < NB; nb++) {
                px[nb] = p[nb * CH + 0]; py[nb] = p[nb * CH + 1];
                pw[nb] = p[nb * CH + 2]; ph[nb] = p[nb * CH + 3];
                float ax1 = px[nb] - pw[nb] * 0.5f, ay1 = py[nb] - ph[nb] * 0.5f;
                float ax2 = px[nb] + pw[nb] * 0.5f, ay2 = py[nb] + ph[nb] * 0.5f;
                float iw = fmaxf(fminf(ax2, bx2) - fmaxf(ax1, bx1), 0.0f);
                float ih = fmaxf(fminf(ay2, by2) - fmaxf(ay1, by1), 0.0f);
                float inter = iw * ih;
                float uni = (ax2 - ax1) * (ay2 - ay1) + barea - inter;
                iou[nb] = inter / (uni + 1e-6f);
            }
            int resp = (iou[1] > iou[0]) ? 1 : 0;
            wq = (resp == 0) ? make_float4(1.f, 1.f, 0.f, 0.f)
                             : make_float4(0.f, 0.f, 1.f, 1.f);

            float pc = p[resp * CH + 4];
            float pl = p[resp * CH + 5 + s_lab[bi]];
            float dx = px[resp] - tx, dy = py[resp] - ty;
            float dw = sqrtf(fmaxf(pw[resp], 1e-6f)) - sqrtf(fmaxf(tw, 1e-6f));
            float dh = sqrtf(fmaxf(ph[resp], 1e-6f)) - sqrtf(fmaxf(th, 1e-6f));
            acc = L_COORD * (dx * dx + dy * dy + dw * dw + dh * dh)
                + (1.0f - 2.0f * pc)      // (p-1)^2 = p^2 + (1-2p)
                + (1.0f - 2.0f * pl);     // sum(p-onehot)^2 = sum p^2 + (1-2p_l)
        } else {
            wq = make_float4(L_NOOBJ, 0.f, L_NOOBJ, 0.f);
        }
        s_wq[tid] = wq;
    }
    __syncthreads();

    // Phase C: coalesced sweep of the pair's 4165 float4s, weights from LDS
    const float4* p = p4 + (size_t)pb * F4_PER_PAIR;
    #pragma unroll
    for (int k = 0; k < 16; ++k) {
        int e = tid + (k << 8);
        acc += elem4(p[e], e, s_wq);
    }
    {
        int e = tid + 4096;
        if (tid < F4_PER_PAIR - 4096) acc += elem4(p[e], e, s_wq);  // 69-wide tail
    }

    block_reduce_store(acc, &partial[pb]);
}

// ---------------- final reduce ----------------
__global__ __launch_bounds__(256) void reduce_kernel(
    const float* __restrict__ partial, int n,
    float* __restrict__ out, float inv_B)
{
    const int tid = threadIdx.x;
    float acc = 0.0f;
    for (int i = tid; i < n; i += 256) acc += partial[i];
    __shared__ float s_wsum[4];
    #pragma unroll
    for (int off = 32; off > 0; off >>= 1) acc += __shfl_down(acc, off, 64);
    int lane = tid & 63, wv = tid >> 6;
    if (lane == 0) s_wsum[wv] = acc;
    __syncthreads();
    if (tid == 0) out[0] = (s_wsum[0] + s_wsum[1] + s_wsum[2] + s_wsum[3]) * inv_B;
}

extern "C" void kernel_launch(void* const* d_in, const int* in_sizes, int n_in,
                              void* d_out, int out_size, void* d_ws, size_t ws_size,
                              hipStream_t stream) {
    const float* pred   = (const float*)d_in[0];
    const float* boxes  = (const float*)d_in[1];
    const int*   labels = (const int*)d_in[2];

    float* partial = (float*)d_ws;   // [NPAIR]

    fused_kernel<<<NPAIR, 256, 0, stream>>>((const float4*)pred,
                                            (const float4*)boxes, labels, partial);
    reduce_kernel<<<1, 256, 0, stream>>>(partial, NPAIR,
                                         (float*)d_out, 1.0f / (float)NIMG);
}

// Round 2
// 198.851 us; speedup vs baseline: 1.0222x; 1.0151x over previous
//
#include <hip/hip_runtime.h>

#define S 7
#define NB 2
#define NC 80
#define NBOX 20
#define CELLS 49
#define CH 85                   // 5 + NC
#define PAIR 170                // NB*CH floats per cell
#define PER_B 8330              // CELLS*PAIR floats per image
#define NIMG 4096
#define IMGS_PER_BLK 2
#define NPAIR (NIMG/IMGS_PER_BLK)          // 2048 blocks
#define F4_PER_PAIR (PER_B*IMGS_PER_BLK/4) // 4165 float4 per pair (exact)
#define CELLS2 (CELLS*IMGS_PER_BLK)        // 98
#define PREF 8                             // prefetch depth (float4 per thread)
#define L_COORD 5.0f
#define L_NOOBJ 0.5f

// ---------------- block reduce helper (256 threads) ----------------
__device__ __forceinline__ void block_reduce_store(float acc, float* dst)
{
    __shared__ float s_wsum[4];
    int tid = threadIdx.x;
    #pragma unroll
    for (int off = 32; off > 0; off >>= 1) acc += __shfl_down(acc, off, 64);
    int lane = tid & 63, wv = tid >> 6;
    if (lane == 0) s_wsum[wv] = acc;
    __syncthreads();
    if (tid == 0) *dst = s_wsum[0] + s_wsum[1] + s_wsum[2] + s_wsum[3];
}

// ---------------- weighted-square element helpers (weights from LDS) -------
__device__ __forceinline__ float elem1(float p, int r, float4 w)
{
    int nb = (r >= CH) ? 1 : 0;
    int rr = r - nb * CH;
    float wconf = nb ? w.z : w.x;
    float wcls  = nb ? w.w : w.y;
    float m = (rr >= 5) ? wcls : ((rr == 4) ? wconf : 0.0f);
    return m * p * p;
}

__device__ __forceinline__ float elem4(float4 v, int e, const float4* s_wq)
{
    // e is the pair-local float4 index (0..4164); ff in [0, 16660)
    unsigned ff = 4u * (unsigned)e;
    unsigned c0 = ff / (unsigned)PAIR;          // magic-mul, c0 in [0,98)
    int r0 = (int)(ff - c0 * (unsigned)PAIR);   // even; straddle only at 168
    float4 w0 = s_wq[c0];
    // Straddle (r0==168): v.z/v.w are channels 0/1 of cell c0+1 -> weight 0
    // regardless of that cell's quad, so w0 is safe for all four elements.
    bool wrap = (r0 == PAIR - 2);
    int r2 = wrap ? 0 : r0 + 2;
    float a;
    a  = elem1(v.x, r0,     w0);
    a += elem1(v.y, r0 + 1, w0);
    a += elem1(v.z, r2,     w0);
    a += elem1(v.w, r2 + 1, w0);
    return a;
}

// ---------------- fused kernel: prefetch + prep (in LDS) + stream ----------
__global__ __launch_bounds__(256) void fused_kernel(
    const float4* __restrict__ p4,      // predictions as float4
    const float4* __restrict__ boxes4,  // [NIMG*NBOX] one float4 per box
    const int*    __restrict__ labels,
    float*        __restrict__ partial) // [NPAIR]
{
    __shared__ int    s_winner[CELLS2];
    __shared__ float  s_cx[IMGS_PER_BLK * NBOX], s_cy[IMGS_PER_BLK * NBOX];
    __shared__ float  s_bw[IMGS_PER_BLK * NBOX], s_bh[IMGS_PER_BLK * NBOX];
    __shared__ int    s_lab[IMGS_PER_BLK * NBOX];
    __shared__ float4 s_wq[CELLS2];

    const int pb  = blockIdx.x;
    const int tid = threadIdx.x;

    // ---- Prefetch: issue the first PREF stream loads before the prologue.
    // They stay in flight (vmcnt) across both barriers; the sweep effectively
    // starts at t=0 instead of after the prologue's latency chains.
    const float4* p = p4 + (size_t)pb * F4_PER_PAIR;
    float4 v[PREF];
    #pragma unroll
    for (int k = 0; k < PREF; ++k) v[k] = p[tid + (k << 8)];

    if (tid < CELLS2) s_winner[tid] = NBOX;
    __syncthreads();

    // Phase A: 40 boxes (2 images) -> cells, winner = min box index per cell
    if (tid < IMGS_PER_BLK * NBOX) {
        int img = tid / NBOX, bxi = tid - img * NBOX;
        size_t gbox = (size_t)(pb * IMGS_PER_BLK + img) * NBOX + bxi;
        float4 bx = boxes4[gbox];
        float x = (bx.x + bx.z) * 0.5f, y = (bx.y + bx.w) * 0.5f;
        s_cx[tid] = x; s_cy[tid] = y;
        s_bw[tid] = bx.z - bx.x; s_bh[tid] = bx.w - bx.y;
        s_lab[tid] = labels[gbox];
        int j = (int)floorf(x * (float)S); j = min(max(j, 0), S - 1);
        int i = (int)floorf(y * (float)S); i = min(max(i, 0), S - 1);
        atomicMin(&s_winner[img * CELLS + i * S + j], bxi);
    }
    __syncthreads();

    // Phase B: responsible box per cell -> weight quad in LDS + corrections
    float acc = 0.0f;
    if (tid < CELLS2) {
        int img  = tid / CELLS;
        int cell = tid - img * CELLS;
        int w    = s_winner[tid];
        float4 wq;
        if (w < NBOX) {
            int i = cell / S, j = cell - (cell / S) * S;
            int bi = img * NBOX + w;
            float x = s_cx[bi], y = s_cy[bi];
            float tx = x * (float)S - (float)j;
            float ty = y * (float)S - (float)i;
            float tw = s_bw[bi], th = s_bh[bi];

            const float* pc0 = (const float*)p4
                             + (size_t)(pb * IMGS_PER_BLK + img) * PER_B
                             + (size_t)cell * PAIR;
            float bx1 = tx - tw * 0.5f, by1 = ty - th * 0.5f;
            float bx2 = tx + tw * 0.5f, by2 = ty + th * 0.5f;
            float barea = (bx2 - bx1) * (by2 - by1);
            float iou[2], px[2], py[2], pw[2], ph[2];
            #pragma unroll
            for (int nb = 0; nb < NB; nb++) {
                px[nb] = pc0[nb * CH + 0]; py[nb] = pc0[nb * CH + 1];
                pw[nb] = pc0[nb * CH + 2]; ph[nb] = pc0[nb * CH + 3];
                float ax1 = px[nb] - pw[nb] * 0.5f, ay1 = py[nb] - ph[nb] * 0.5f;
                float ax2 = px[nb] + pw[nb] * 0.5f, ay2 = py[nb] + ph[nb] * 0.5f;
                float iw = fmaxf(fminf(ax2, bx2) - fmaxf(ax1, bx1), 0.0f);
                float ih = fmaxf(fminf(ay2, by2) - fmaxf(ay1, by1), 0.0f);
                float inter = iw * ih;
                float uni = (ax2 - ax1) * (ay2 - ay1) + barea - inter;
                iou[nb] = inter / (uni + 1e-6f);
            }
            int resp = (iou[1] > iou[0]) ? 1 : 0;
            wq = (resp == 0) ? make_float4(1.f, 1.f, 0.f, 0.f)
                             : make_float4(0.f, 0.f, 1.f, 1.f);

            float pc = pc0[resp * CH + 4];
            float pl = pc0[resp * CH + 5 + s_lab[bi]];
            float dx = px[resp] - tx, dy = py[resp] - ty;
            float dw = sqrtf(fmaxf(pw[resp], 1e-6f)) - sqrtf(fmaxf(tw, 1e-6f));
            float dh = sqrtf(fmaxf(ph[resp], 1e-6f)) - sqrtf(fmaxf(th, 1e-6f));
            acc = L_COORD * (dx * dx + dy * dy + dw * dw + dh * dh)
                + (1.0f - 2.0f * pc)      // (p-1)^2 = p^2 + (1-2p)
                + (1.0f - 2.0f * pl);     // sum(p-onehot)^2 = sum p^2 + (1-2p_l)
        } else {
            wq = make_float4(L_NOOBJ, 0.f, L_NOOBJ, 0.f);
        }
        s_wq[tid] = wq;
    }
    __syncthreads();

    // Phase C: consume prefetched chunks, then sweep the rest coalesced
    #pragma unroll
    for (int k = 0; k < PREF; ++k)
        acc += elem4(v[k], tid + (k << 8), s_wq);
    #pragma unroll
    for (int k = PREF; k < 16; ++k) {
        int e = tid + (k << 8);
        acc += elem4(p[e], e, s_wq);
    }
    {
        int e = tid + 4096;
        if (tid < F4_PER_PAIR - 4096) acc += elem4(p[e], e, s_wq);  // 69-wide tail
    }

    block_reduce_store(acc, &partial[pb]);
}

// ---------------- final reduce ----------------
__global__ __launch_bounds__(256) void reduce_kernel(
    const float* __restrict__ partial, int n,
    float* __restrict__ out, float inv_B)
{
    const int tid = threadIdx.x;
    float acc = 0.0f;
    const float4* p4 = (const float4*)partial;
    for (int i = tid; i < n / 4; i += 256) {
        float4 v = p4[i];
        acc += (v.x + v.y) + (v.z + v.w);
    }
    __shared__ float s_wsum[4];
    #pragma unroll
    for (int off = 32; off > 0; off >>= 1) acc += __shfl_down(acc, off, 64);
    int lane = tid & 63, wv = tid >> 6;
    if (lane == 0) s_wsum[wv] = acc;
    __syncthreads();
    if (tid == 0) out[0] = (s_wsum[0] + s_wsum[1] + s_wsum[2] + s_wsum[3]) * inv_B;
}

extern "C" void kernel_launch(void* const* d_in, const int* in_sizes, int n_in,
                              void* d_out, int out_size, void* d_ws, size_t ws_size,
                              hipStream_t stream) {
    const float* pred   = (const float*)d_in[0];
    const float* boxes  = (const float*)d_in[1];
    const int*   labels = (const int*)d_in[2];

    float* partial = (float*)d_ws;   // [NPAIR], NPAIR % 4 == 0

    fused_kernel<<<NPAIR, 256, 0, stream>>>((const float4*)pred,
                                            (const float4*)boxes, labels, partial);
    reduce_kernel<<<1, 256, 0, stream>>>(partial, NPAIR,
                                         (float*)d_out, 1.0f / (float)NIMG);
}